// Round 7
// baseline (388.302 us; speedup 1.0000x reference)
//
#include <hip/hip_runtime.h>
#include <hip/hip_bf16.h>

#define FEAT 128
#define NRELS 8
#define KTOT 1024          // NRELS * FEAT
#define BN 32              // dst nodes per aggemm block
#define ECAP 512           // edges sorted per chunk

typedef __bf16 bf16_t;
typedef __bf16 bf16x2_t __attribute__((ext_vector_type(2)));
typedef __bf16 bf16x8_t __attribute__((ext_vector_type(8)));
typedef float f32x4 __attribute__((ext_vector_type(4)));

struct __align__(8) PackedEdge { int row; float scale; };
// row = (src<<8) | (local<<3) | rel ; key = row & 255 ; src = row >> 8

static inline size_t align256(size_t x) { return (x + 255) & ~(size_t)255; }

// ---------------------------------------------------------------------------
// Fused phase 1: [0,nprep) blocks = h->hb convert + gate; [nprep,nprep+ndeg) =
// per-32-node-block degree count; rest = w -> wt2 [f][r*128+d] convert.
__global__ __launch_bounds__(256) void k_phase1(const float* __restrict__ h,
                                                const float* __restrict__ gw,
                                                const int* __restrict__ dstv,
                                                const float* __restrict__ w,
                                                float* __restrict__ sg,
                                                bf16_t* __restrict__ hb,
                                                int* __restrict__ degb,
                                                bf16_t* __restrict__ wt2,
                                                int nprep, int ndeg, int N, int E) {
    const int b = blockIdx.x;
    const int t = threadIdx.x;
    if (b < nprep) {
        // ---- prep: convert + gate (verified round 4/6 structure) ----
        int wv = b * 4 + (t >> 6);
        int lane = t & 63;
        if (wv >= N) return;
        float2 hv2 = *reinterpret_cast<const float2*>(h + (size_t)wv * FEAT + lane * 2);
        bf16x2_t hc;
        hc.x = (bf16_t)hv2.x;
        hc.y = (bf16_t)hv2.y;
        *reinterpret_cast<bf16x2_t*>(hb + (size_t)wv * FEAT + lane * 2) = hc;

        int r = lane >> 3;
        int g = lane & 7;
        const float4* hp = reinterpret_cast<const float4*>(h + (size_t)wv * FEAT + g * 16);
        const float4* wp = reinterpret_cast<const float4*>(gw + r * FEAT + g * 16);
        float s = 0.f;
#pragma unroll
        for (int i = 0; i < 4; ++i) {
            float4 a = hp[i];
            float4 bb = wp[i];
            s += a.x * bb.x + a.y * bb.y + a.z * bb.z + a.w * bb.w;
        }
        s += __shfl_xor(s, 1, 64);
        s += __shfl_xor(s, 2, 64);
        s += __shfl_xor(s, 4, 64);
        if (g == 0) sg[(size_t)wv * NRELS + r] = 1.0f / (1.0f + __expf(-s));
    } else if (b < nprep + ndeg) {
        int e = (b - nprep) * 256 + t;
        if (e < E) atomicAdd(&degb[dstv[e] >> 5], 1);   // BN = 32
    } else {
        int i = (b - nprep - ndeg) * 256 + t;
        if (i < NRELS * FEAT * FEAT) {
            int r = i >> 14;
            int rem = i & 16383;
            int d = rem >> 7;
            int f = rem & 127;
            wt2[(size_t)f * KTOT + r * FEAT + d] = (bf16_t)w[i];
        }
    }
}

// ---------------------------------------------------------------------------
// Single-block scan over nbk (~3125) block counts; writes base[] (exclusive),
// cur[] (working cursor copy), base[nbk] = total.
__global__ __launch_bounds__(1024) void k_scan_one(const int* __restrict__ deg,
                                                   int* __restrict__ base,
                                                   int* __restrict__ cur, int nb) {
    __shared__ int sm[1024];
    __shared__ int carry;
    int t = threadIdx.x;
    if (t == 0) carry = 0;
    __syncthreads();
    for (int s0 = 0; s0 < nb; s0 += 1024) {
        int v = (s0 + t < nb) ? deg[s0 + t] : 0;
        sm[t] = v;
        __syncthreads();
        for (int off = 1; off < 1024; off <<= 1) {
            int x = (t >= off) ? sm[t - off] : 0;
            __syncthreads();
            sm[t] += x;
            __syncthreads();
        }
        if (s0 + t < nb) {
            int ex = carry + sm[t] - v;
            base[s0 + t] = ex;
            cur[s0 + t] = ex;
        }
        int tot = sm[1023];
        __syncthreads();
        if (t == 0) carry += tot;
        __syncthreads();
    }
    if (t == 0) base[nb] = carry;
}

// ---------------------------------------------------------------------------
// Fill packed records into per-32-node-block buckets (unsorted within bucket;
// k_aggemm counting-sorts in LDS).
__global__ void k_fillb(const int* __restrict__ src, const int* __restrict__ dstv,
                        const int* __restrict__ rel, const float* __restrict__ nrm,
                        const float* __restrict__ sg, int* __restrict__ cur,
                        PackedEdge* __restrict__ packed, int nedges) {
    int e = blockIdx.x * blockDim.x + threadIdx.x;
    if (e >= nedges) return;
    int d = dstv[e];
    int s = src[e];
    int r = rel[e];
    int pos = atomicAdd(&cur[d >> 5], 1);
    PackedEdge p;
    p.row = (s << 8) | ((d & 31) << 3) | r;
    p.scale = nrm[e] * sg[(size_t)s * NRELS + r];
    packed[pos] = p;
}

// ---------------------------------------------------------------------------
// Fused sort + aggregate + GEMM + relu. Block = 512 threads (8 waves), 32 dst
// nodes. LDS: agg bf16 [32][2048B] XOR-swizzled (64KB) + elist (4KB) + sort
// tables (~3KB) = ~71KB -> 2 blocks/CU.
//
// Prologue per <=512-edge chunk: coalesced load of the block's bucket into
//   registers, LDS counting sort over 256 keys (local*8+rel): count (LDS
//   atomics) -> 64-lane shfl scan -> scatter. Packed traffic is read ONCE,
//   coalesced (vs 8B-granule strided before).
// Phase A: one 16-lane group per node; records via free LDS broadcasts; only
//   hb rows are global (depth-4 ring). Flush per rel-run = LDS RMW add
//   (correct across chunks; single chunk == plain store on zeros).
// Phase B: M=32 x N=128 x K=1024 MFMA GEMM; bv (wt2) 4-deep register prefetch,
//   first 4 issued at kernel top (hidden under phase A). C -> aliased LDS
//   [32][132]; relu + coalesced float4 stores.
__global__ __launch_bounds__(512, 4) void k_aggemm(const bf16_t* __restrict__ hb,
                                                   const bf16_t* __restrict__ wt2,
                                                   const PackedEdge* __restrict__ packed,
                                                   const int* __restrict__ bbase,
                                                   float* __restrict__ out, int nnodes) {
    __shared__ __align__(16) char lds_raw[BN * KTOT * sizeof(bf16_t)];   // 64 KiB
    __shared__ __align__(8) PackedEdge elist[ECAP];
    __shared__ int kcnt[256];
    __shared__ int kbase[257];
    __shared__ int kwork[256];
    float* cst = (float*)lds_raw;                 // aliased C-stage [32][132]
    const int t = threadIdx.x;
    const int nb0 = blockIdx.x * BN;
    const int lane = t & 63;
    const int wv = t >> 6;               // 0..7
    const int l15 = lane & 15;
    const int lhi = lane >> 4;

    // Phase-B bv preload (completes during phase A)
    const bf16_t* bp = wt2 + (size_t)(wv * 16 + l15) * KTOT + lhi * 8;
    bf16x8_t bv0 = *reinterpret_cast<const bf16x8_t*>(bp);
    bf16x8_t bv1 = *reinterpret_cast<const bf16x8_t*>(bp + 32);
    bf16x8_t bv2 = *reinterpret_cast<const bf16x8_t*>(bp + 64);
    bf16x8_t bv3 = *reinterpret_cast<const bf16x8_t*>(bp + 96);

    // zero agg tile
    {
        f32x4 z = {0.f, 0.f, 0.f, 0.f};
#pragma unroll
        for (int i = 0; i < 8; ++i)
            reinterpret_cast<f32x4*>(lds_raw)[t + i * 512] = z;
    }

    const int ebeg = bbase[blockIdx.x];
    const int etot = bbase[blockIdx.x + 1] - ebeg;

    for (int done = 0; done < etot; done += ECAP) {
        const int nE = min(etot - done, ECAP);
        if (t < 256) kcnt[t] = 0;
        __syncthreads();

        // coalesced bucket load + count
        PackedEdge myrec = {0, 0.f};
        if (t < nE) {
            myrec = packed[ebeg + done + t];
            atomicAdd(&kcnt[myrec.row & 255], 1);
        }
        __syncthreads();

        // 64-lane shfl scan over 256 counters (wave 0)
        if (t < 64) {
            int c0 = kcnt[t * 4], c1 = kcnt[t * 4 + 1];
            int c2 = kcnt[t * 4 + 2], c3 = kcnt[t * 4 + 3];
            int tot = c0 + c1 + c2 + c3;
            int incl = tot;
#pragma unroll
            for (int off = 1; off < 64; off <<= 1) {
                int y = __shfl_up(incl, off, 64);
                if (t >= off) incl += y;
            }
            int excl = incl - tot;
            kbase[t * 4] = excl;               kwork[t * 4] = excl;
            kbase[t * 4 + 1] = excl + c0;      kwork[t * 4 + 1] = excl + c0;
            kbase[t * 4 + 2] = excl + c0 + c1; kwork[t * 4 + 2] = excl + c0 + c1;
            kbase[t * 4 + 3] = excl + c0 + c1 + c2;
            kwork[t * 4 + 3] = excl + c0 + c1 + c2;
            if (t == 63) kbase[256] = excl + tot;   // = nE
        }
        __syncthreads();

        // scatter into sorted elist
        if (t < nE) elist[atomicAdd(&kwork[myrec.row & 255], 1)] = myrec;
        __syncthreads();

        // ---------------- Phase A: per-node aggregation ----------------
        {
            const int g = t >> 4;            // group = local node 0..31
            const int il = t & 15;
            const int sw = g & 7;
            const int jbeg = kbase[g * 8];
            const int jend = kbase[g * 8 + 8];
            if (jbeg < jend) {
                float a[8];
#pragma unroll
                for (int i = 0; i < 8; ++i) a[i] = 0.f;
                int cur_r;

                auto ldrec = [&](int idx) {
                    return elist[idx < jend ? idx : jend - 1];   // LDS broadcast
                };
                auto ldrow = [&](const PackedEdge& p) {
                    return *reinterpret_cast<const bf16x8_t*>(
                        hb + ((size_t)(p.row >> 8) << 7) + il * 8);
                };
                auto flush = [&](int rr) {       // RMW add (zeros on 1st chunk)
                    int chunk = (rr * 16 + il) ^ sw;
                    bf16_t* dp = reinterpret_cast<bf16_t*>(
                        lds_raw + (size_t)g * 2048 + chunk * 16);
                    bf16x8_t old = *reinterpret_cast<const bf16x8_t*>(dp);
                    bf16x8_t o;
#pragma unroll
                    for (int i = 0; i < 8; ++i) o[i] = (bf16_t)((float)old[i] + a[i]);
                    *reinterpret_cast<bf16x8_t*>(dp) = o;
                };
                auto consume = [&](const PackedEdge& p, const bf16x8_t& v, int idx) {
                    if (idx < jend) {
                        int r = p.row & 7;
                        if (r != cur_r) {        // group-uniform branch
                            flush(cur_r);
#pragma unroll
                            for (int i = 0; i < 8; ++i) a[i] = 0.f;
                            cur_r = r;
                        }
                        float s = p.scale;
#pragma unroll
                        for (int i = 0; i < 8; ++i) a[i] += (float)v[i] * s;
                    }
                };

                PackedEdge p0 = ldrec(jbeg), p1 = ldrec(jbeg + 1);
                PackedEdge p2 = ldrec(jbeg + 2), p3 = ldrec(jbeg + 3);
                PackedEdge q0 = ldrec(jbeg + 4), q1 = ldrec(jbeg + 5);
                PackedEdge q2 = ldrec(jbeg + 6), q3 = ldrec(jbeg + 7);
                bf16x8_t v0 = ldrow(p0);
                bf16x8_t v1 = ldrow(p1);
                bf16x8_t v2 = ldrow(p2);
                bf16x8_t v3 = ldrow(p3);
                cur_r = p0.row & 7;

#pragma unroll 1
                for (int j = jbeg; j < jend; j += 4) {
                    PackedEdge r0 = ldrec(j + 8), r1 = ldrec(j + 9);
                    PackedEdge r2 = ldrec(j + 10), r3 = ldrec(j + 11);
                    consume(p0, v0, j);
                    consume(p1, v1, j + 1);
                    consume(p2, v2, j + 2);
                    consume(p3, v3, j + 3);
                    v0 = ldrow(q0); v1 = ldrow(q1); v2 = ldrow(q2); v3 = ldrow(q3);
                    p0 = q0; p1 = q1; p2 = q2; p3 = q3;
                    q0 = r0; q1 = r1; q2 = r2; q3 = r3;
                }
                flush(cur_r);
            }
        }
        __syncthreads();
    }
    __syncthreads();   // covers etot==0 path (agg zeroed above)

    // ---------------- Phase B: GEMM with 4-deep bv prefetch ----------------
    f32x4 acc0 = {0.f, 0.f, 0.f, 0.f};
    f32x4 acc1 = {0.f, 0.f, 0.f, 0.f};
    const char* a0p = lds_raw + (size_t)l15 * 2048;        // node rows 0..15
    const char* a1p = a0p + 16 * 2048;                     // node rows 16..31
    const int swb = l15 & 7;

#define PB_STEP(I, BV)                                                         \
    {                                                                          \
        int ks = ks0 + (I);                                                    \
        int coff = ((ks * 4 + lhi) ^ swb) << 4;                                \
        bf16x8_t av0 = *reinterpret_cast<const bf16x8_t*>(a0p + coff);         \
        bf16x8_t av1 = *reinterpret_cast<const bf16x8_t*>(a1p + coff);         \
        bf16x8_t nxt = *reinterpret_cast<const bf16x8_t*>(                     \
            bp + (((ks + 4) & 31) * 32));                                      \
        acc0 = __builtin_amdgcn_mfma_f32_16x16x32_bf16(av0, BV, acc0, 0, 0, 0);\
        acc1 = __builtin_amdgcn_mfma_f32_16x16x32_bf16(av1, BV, acc1, 0, 0, 0);\
        BV = nxt;                                                              \
    }

#pragma unroll 1
    for (int ks0 = 0; ks0 < 32; ks0 += 4) {
        PB_STEP(0, bv0)
        PB_STEP(1, bv1)
        PB_STEP(2, bv2)
        PB_STEP(3, bv3)
    }
#undef PB_STEP
    __syncthreads();   // all agg reads done; safe to overwrite with C

    // C layout: col(l15)=f within wave slice, row(lhi*4+i)=node (m89-verified)
    {
        int f = wv * 16 + l15;
#pragma unroll
        for (int i = 0; i < 4; ++i) {
            int n0 = lhi * 4 + i;
            cst[n0 * 132 + f] = acc0[i];
            cst[(n0 + 16) * 132 + f] = acc1[i];
        }
    }
    __syncthreads();

    // relu + coalesced store: thread t -> node t>>4, feats (t&15)*8..+8
    {
        int node = t >> 4;
        int f0 = (t & 15) * 8;
        int gnode = nb0 + node;
        if (gnode < nnodes) {
            const float* cr = cst + node * 132 + f0;
            float4 o0, o1;
            o0.x = fmaxf(cr[0], 0.f); o0.y = fmaxf(cr[1], 0.f);
            o0.z = fmaxf(cr[2], 0.f); o0.w = fmaxf(cr[3], 0.f);
            o1.x = fmaxf(cr[4], 0.f); o1.y = fmaxf(cr[5], 0.f);
            o1.z = fmaxf(cr[6], 0.f); o1.w = fmaxf(cr[7], 0.f);
            float4* op = reinterpret_cast<float4*>(out + (size_t)gnode * FEAT + f0);
            op[0] = o0;
            op[1] = o1;
        }
    }
}

// ---------------------------------------------------------------------------
extern "C" void kernel_launch(void* const* d_in, const int* in_sizes, int n_in,
                              void* d_out, int out_size, void* d_ws, size_t ws_size,
                              hipStream_t stream) {
    const float* h = (const float*)d_in[0];
    const float* w = (const float*)d_in[1];
    const float* gw = (const float*)d_in[2];
    const float* nrm = (const float*)d_in[3];
    const int* src = (const int*)d_in[4];
    const int* dst = (const int*)d_in[5];
    const int* rel = (const int*)d_in[6];
    float* out = (float*)d_out;

    const int N = in_sizes[0] / FEAT;
    const int E = in_sizes[4];
    const int nbk = (N + BN - 1) / BN;

    char* ws = (char*)d_ws;
    const size_t wt2B = align256((size_t)FEAT * KTOT * sizeof(bf16_t));   // 256 KiB
    const size_t hbB  = align256((size_t)N * FEAT * sizeof(bf16_t));      // 25.6 MB
    const size_t sgB  = align256((size_t)N * NRELS * sizeof(float));      // 3.2 MB
    const size_t dgB  = align256((size_t)nbk * sizeof(int));
    const size_t bbB  = align256((size_t)(nbk + 1) * sizeof(int));
    const size_t cuB  = align256((size_t)nbk * sizeof(int));

    bf16_t* wt2 = (bf16_t*)ws;
    bf16_t* hb = (bf16_t*)(ws + wt2B);
    float* sg = (float*)(ws + wt2B + hbB);
    int* degb = (int*)(ws + wt2B + hbB + sgB);
    int* bbase = (int*)(ws + wt2B + hbB + sgB + dgB);
    int* cur = (int*)(ws + wt2B + hbB + sgB + dgB + bbB);
    PackedEdge* packed = (PackedEdge*)(ws + wt2B + hbB + sgB + dgB + bbB + cuB);

    const int nprep = (N + 3) / 4;
    const int ndeg = (E + 255) / 256;
    const int nwcv = (NRELS * FEAT * FEAT + 255) / 256;

    hipMemsetAsync(degb, 0, (size_t)nbk * sizeof(int), stream);
    k_phase1<<<nprep + ndeg + nwcv, 256, 0, stream>>>(h, gw, dst, w, sg, hb, degb,
                                                      wt2, nprep, ndeg, N, E);
    k_scan_one<<<1, 1024, 0, stream>>>(degb, bbase, cur, nbk);
    k_fillb<<<(E + 255) / 256, 256, 0, stream>>>(src, dst, rel, nrm, sg, cur,
                                                 packed, E);
    k_aggemm<<<nbk, 512, 0, stream>>>(hb, wt2, packed, bbase, out, N);
}

// Round 8
// 311.250 us; speedup vs baseline: 1.2476x; 1.2476x over previous
//
#include <hip/hip_runtime.h>
#include <hip/hip_bf16.h>

#define FEAT 128
#define NRELS 8
#define KTOT 1024          // NRELS * FEAT
#define BN 32              // dst nodes per aggemm block
#define ECAP 256           // slab capacity per 32-node bucket (avg ~192)
#define CPAD 16            // cursor padding: one int per 64B line

typedef __bf16 bf16_t;
typedef __bf16 bf16x2_t __attribute__((ext_vector_type(2)));
typedef __bf16 bf16x8_t __attribute__((ext_vector_type(8)));
typedef float f32x4 __attribute__((ext_vector_type(4)));

struct __align__(8) PackedEdge { int row; float scale; };
// row = (src<<8) | (local<<3) | rel ; key = row & 255 ; src = row >> 8

static inline size_t align256(size_t x) { return (x + 255) & ~(size_t)255; }

// ---------------------------------------------------------------------------
// Fused phase 1: [0,nprep) blocks = h->hb convert + gate; rest = w->wt2.
__global__ __launch_bounds__(256) void k_phase1(const float* __restrict__ h,
                                                const float* __restrict__ gw,
                                                const float* __restrict__ w,
                                                float* __restrict__ sg,
                                                bf16_t* __restrict__ hb,
                                                bf16_t* __restrict__ wt2,
                                                int nprep, int N) {
    const int b = blockIdx.x;
    const int t = threadIdx.x;
    if (b < nprep) {
        // ---- prep: convert + gate (verified rounds 4-7) ----
        int wv = b * 4 + (t >> 6);
        int lane = t & 63;
        if (wv >= N) return;
        float2 hv2 = *reinterpret_cast<const float2*>(h + (size_t)wv * FEAT + lane * 2);
        bf16x2_t hc;
        hc.x = (bf16_t)hv2.x;
        hc.y = (bf16_t)hv2.y;
        *reinterpret_cast<bf16x2_t*>(hb + (size_t)wv * FEAT + lane * 2) = hc;

        int r = lane >> 3;
        int g = lane & 7;
        const float4* hp = reinterpret_cast<const float4*>(h + (size_t)wv * FEAT + g * 16);
        const float4* wp = reinterpret_cast<const float4*>(gw + r * FEAT + g * 16);
        float s = 0.f;
#pragma unroll
        for (int i = 0; i < 4; ++i) {
            float4 a = hp[i];
            float4 bb = wp[i];
            s += a.x * bb.x + a.y * bb.y + a.z * bb.z + a.w * bb.w;
        }
        s += __shfl_xor(s, 1, 64);
        s += __shfl_xor(s, 2, 64);
        s += __shfl_xor(s, 4, 64);
        if (g == 0) sg[(size_t)wv * NRELS + r] = 1.0f / (1.0f + __expf(-s));
    } else {
        int i = (b - nprep) * 256 + t;
        if (i < NRELS * FEAT * FEAT) {
            int r = i >> 14;
            int rem = i & 16383;
            int d = rem >> 7;
            int f = rem & 127;
            wt2[(size_t)f * KTOT + r * FEAT + d] = (bf16_t)w[i];
        }
    }
}

// ---------------------------------------------------------------------------
// Atomic-append fill into fixed-capacity per-bucket slabs. Cursors padded to
// one per cache line (round-7 lesson: 16 cursors/line serialized ~3000 RMWs).
// No degree pass, no scan pass. Overflow (rare; avg fill 192/256) -> global
// list drained by k_aggemm's rare path.
__global__ void k_fills(const int* __restrict__ src, const int* __restrict__ dstv,
                        const int* __restrict__ rel, const float* __restrict__ nrm,
                        const float* __restrict__ sg, int* __restrict__ cur,
                        PackedEdge* __restrict__ slab, PackedEdge* __restrict__ ovfrec,
                        int* __restrict__ ovfbk, int* __restrict__ ovfcnt, int nedges) {
    int e = blockIdx.x * blockDim.x + threadIdx.x;
    if (e >= nedges) return;
    int d = dstv[e];
    int s = src[e];
    int r = rel[e];
    int bk = d >> 5;
    PackedEdge p;
    p.row = (s << 8) | ((d & 31) << 3) | r;
    p.scale = nrm[e] * sg[(size_t)s * NRELS + r];
    int pos = atomicAdd(&cur[bk * CPAD], 1);
    if (pos < ECAP) {
        slab[(size_t)bk * ECAP + pos] = p;
    } else {
        int op = atomicAdd(ovfcnt, 1);
        ovfrec[op] = p;
        ovfbk[op] = bk;
    }
}

// ---------------------------------------------------------------------------
// Fused sort + aggregate + GEMM + relu. Block = 512 threads (8 waves), 32 dst
// nodes. LDS: agg bf16 [32][2048B] XOR-swizzled at 16B chunks, chunk^(node&15)
// (full 16-slot XOR -> 2-way banks, free; round-7's &7 caused 6.5M conflict
// cycles). 64KB agg + ~7KB sort = 2 blocks/CU.
__global__ __launch_bounds__(512, 4) void k_aggemm(const bf16_t* __restrict__ hb,
                                                   const bf16_t* __restrict__ wt2,
                                                   const PackedEdge* __restrict__ slab,
                                                   const int* __restrict__ cur,
                                                   const PackedEdge* __restrict__ ovfrec,
                                                   const int* __restrict__ ovfbk,
                                                   const int* __restrict__ ovfcnt,
                                                   float* __restrict__ out, int nnodes) {
    __shared__ __align__(16) char lds_raw[BN * KTOT * sizeof(bf16_t)];   // 64 KiB
    __shared__ __align__(8) PackedEdge elist[ECAP];
    __shared__ int kcnt[256];
    __shared__ int kbase[257];
    __shared__ int kwork[256];
    float* cst = (float*)lds_raw;                 // aliased C-stage [32][132]
    const int t = threadIdx.x;
    const int nb0 = blockIdx.x * BN;
    const int lane = t & 63;
    const int wv = t >> 6;               // 0..7
    const int l15 = lane & 15;
    const int lhi = lane >> 4;

    // Phase-B bv preload (completes during sort/phase A)
    const bf16_t* bp = wt2 + (size_t)(wv * 16 + l15) * KTOT + lhi * 8;
    bf16x8_t bv0 = *reinterpret_cast<const bf16x8_t*>(bp);
    bf16x8_t bv1 = *reinterpret_cast<const bf16x8_t*>(bp + 32);
    bf16x8_t bv2 = *reinterpret_cast<const bf16x8_t*>(bp + 64);
    bf16x8_t bv3 = *reinterpret_cast<const bf16x8_t*>(bp + 96);

    // zero agg tile
    {
        f32x4 z = {0.f, 0.f, 0.f, 0.f};
#pragma unroll
        for (int i = 0; i < 8; ++i)
            reinterpret_cast<f32x4*>(lds_raw)[t + i * 512] = z;
    }

    const int cnt = cur[blockIdx.x * CPAD];
    const int nE = cnt < ECAP ? cnt : ECAP;
    if (t < 256) kcnt[t] = 0;
    __syncthreads();

    // coalesced slab load + count
    PackedEdge myrec = {0, 0.f};
    if (t < nE) {
        myrec = slab[(size_t)blockIdx.x * ECAP + t];
        atomicAdd(&kcnt[myrec.row & 255], 1);
    }
    __syncthreads();

    // 64-lane shfl scan over 256 counters (wave 0)
    if (t < 64) {
        int c0 = kcnt[t * 4], c1 = kcnt[t * 4 + 1];
        int c2 = kcnt[t * 4 + 2], c3 = kcnt[t * 4 + 3];
        int tot = c0 + c1 + c2 + c3;
        int incl = tot;
#pragma unroll
        for (int off = 1; off < 64; off <<= 1) {
            int y = __shfl_up(incl, off, 64);
            if (t >= off) incl += y;
        }
        int excl = incl - tot;
        kbase[t * 4] = excl;               kwork[t * 4] = excl;
        kbase[t * 4 + 1] = excl + c0;      kwork[t * 4 + 1] = excl + c0;
        kbase[t * 4 + 2] = excl + c0 + c1; kwork[t * 4 + 2] = excl + c0 + c1;
        kbase[t * 4 + 3] = excl + c0 + c1 + c2;
        kwork[t * 4 + 3] = excl + c0 + c1 + c2;
        if (t == 63) kbase[256] = excl + tot;   // = nE
    }
    __syncthreads();

    // scatter into sorted elist
    if (t < nE) elist[atomicAdd(&kwork[myrec.row & 255], 1)] = myrec;
    __syncthreads();

    // ---------------- Phase A: per-node aggregation ----------------
    {
        const int g = t >> 4;            // group = local node 0..31
        const int il = t & 15;
        const int sw = g & 15;
        const int jbeg = kbase[g * 8];
        const int jend = kbase[g * 8 + 8];
        if (jbeg < jend) {
            float a[8];
#pragma unroll
            for (int i = 0; i < 8; ++i) a[i] = 0.f;
            int cur_r;

            auto ldrec = [&](int idx) {
                return elist[idx < jend ? idx : jend - 1];   // LDS broadcast
            };
            auto ldrow = [&](const PackedEdge& p) {
                return *reinterpret_cast<const bf16x8_t*>(
                    hb + ((size_t)(p.row >> 8) << 7) + il * 8);
            };
            auto flush = [&](int rr) {       // RMW add (zeros on first touch)
                int chunk = (rr * 16 + il) ^ sw;
                bf16_t* dp = reinterpret_cast<bf16_t*>(
                    lds_raw + (size_t)g * 2048 + chunk * 16);
                bf16x8_t old = *reinterpret_cast<const bf16x8_t*>(dp);
                bf16x8_t o;
#pragma unroll
                for (int i = 0; i < 8; ++i) o[i] = (bf16_t)((float)old[i] + a[i]);
                *reinterpret_cast<bf16x8_t*>(dp) = o;
            };
            auto consume = [&](const PackedEdge& p, const bf16x8_t& v, int idx) {
                if (idx < jend) {
                    int r = p.row & 7;
                    if (r != cur_r) {        // group-uniform branch
                        flush(cur_r);
#pragma unroll
                        for (int i = 0; i < 8; ++i) a[i] = 0.f;
                        cur_r = r;
                    }
                    float s = p.scale;
#pragma unroll
                    for (int i = 0; i < 8; ++i) a[i] += (float)v[i] * s;
                }
            };

            PackedEdge p0 = ldrec(jbeg), p1 = ldrec(jbeg + 1);
            PackedEdge p2 = ldrec(jbeg + 2), p3 = ldrec(jbeg + 3);
            PackedEdge q0 = ldrec(jbeg + 4), q1 = ldrec(jbeg + 5);
            PackedEdge q2 = ldrec(jbeg + 6), q3 = ldrec(jbeg + 7);
            bf16x8_t v0 = ldrow(p0);
            bf16x8_t v1 = ldrow(p1);
            bf16x8_t v2 = ldrow(p2);
            bf16x8_t v3 = ldrow(p3);
            cur_r = p0.row & 7;

#pragma unroll 1
            for (int j = jbeg; j < jend; j += 4) {
                PackedEdge r0 = ldrec(j + 8), r1 = ldrec(j + 9);
                PackedEdge r2 = ldrec(j + 10), r3 = ldrec(j + 11);
                consume(p0, v0, j);
                consume(p1, v1, j + 1);
                consume(p2, v2, j + 2);
                consume(p3, v3, j + 3);
                v0 = ldrow(q0); v1 = ldrow(q1); v2 = ldrow(q2); v3 = ldrow(q3);
                p0 = q0; p1 = q1; p2 = q2; p3 = q3;
                q0 = r0; q1 = r1; q2 = r2; q3 = r3;
            }
            flush(cur_r);
        }

        // -------- rare overflow drain (normally novf == 0) --------
        int novf = *ovfcnt;
        if (novf > 0) {
#pragma unroll 1
            for (int i = 0; i < novf; ++i) {
                if (ovfbk[i] != blockIdx.x) continue;
                PackedEdge p = ovfrec[i];
                if (((p.row >> 3) & 31) != g) continue;
                bf16x8_t v = *reinterpret_cast<const bf16x8_t*>(
                    hb + ((size_t)(p.row >> 8) << 7) + il * 8);
                int chunk = ((p.row & 7) * 16 + il) ^ sw;
                bf16_t* dp = reinterpret_cast<bf16_t*>(
                    lds_raw + (size_t)g * 2048 + chunk * 16);
                bf16x8_t old = *reinterpret_cast<const bf16x8_t*>(dp);
                bf16x8_t o;
#pragma unroll
                for (int k = 0; k < 8; ++k)
                    o[k] = (bf16_t)((float)old[k] + (float)v[k] * p.scale);
                *reinterpret_cast<bf16x8_t*>(dp) = o;
            }
        }
    }
    __syncthreads();

    // ---------------- Phase B: GEMM with 4-deep bv prefetch ----------------
    f32x4 acc0 = {0.f, 0.f, 0.f, 0.f};
    f32x4 acc1 = {0.f, 0.f, 0.f, 0.f};
    const char* a0p = lds_raw + (size_t)l15 * 2048;        // node rows 0..15
    const char* a1p = a0p + 16 * 2048;                     // node rows 16..31
    const int swb = l15;                 // (16+l15)&15 == l15 : matches write

#define PB_STEP(I, BV)                                                         \
    {                                                                          \
        int ks = ks0 + (I);                                                    \
        int coff = ((ks * 4 + lhi) ^ swb) << 4;                                \
        bf16x8_t av0 = *reinterpret_cast<const bf16x8_t*>(a0p + coff);         \
        bf16x8_t av1 = *reinterpret_cast<const bf16x8_t*>(a1p + coff);         \
        bf16x8_t nxt = *reinterpret_cast<const bf16x8_t*>(                     \
            bp + (((ks + 4) & 31) * 32));                                      \
        acc0 = __builtin_amdgcn_mfma_f32_16x16x32_bf16(av0, BV, acc0, 0, 0, 0);\
        acc1 = __builtin_amdgcn_mfma_f32_16x16x32_bf16(av1, BV, acc1, 0, 0, 0);\
        BV = nxt;                                                              \
    }

#pragma unroll 1
    for (int ks0 = 0; ks0 < 32; ks0 += 4) {
        PB_STEP(0, bv0)
        PB_STEP(1, bv1)
        PB_STEP(2, bv2)
        PB_STEP(3, bv3)
    }
#undef PB_STEP
    __syncthreads();   // all agg reads done; safe to overwrite with C

    // C layout: col(l15)=f within wave slice, row(lhi*4+i)=node (m89-verified)
    {
        int f = wv * 16 + l15;
#pragma unroll
        for (int i = 0; i < 4; ++i) {
            int n0 = lhi * 4 + i;
            cst[n0 * 132 + f] = acc0[i];
            cst[(n0 + 16) * 132 + f] = acc1[i];
        }
    }
    __syncthreads();

    // relu + coalesced store: thread t -> node t>>4, feats (t&15)*8..+8
    {
        int node = t >> 4;
        int f0 = (t & 15) * 8;
        int gnode = nb0 + node;
        if (gnode < nnodes) {
            const float* cr = cst + node * 132 + f0;
            float4 o0, o1;
            o0.x = fmaxf(cr[0], 0.f); o0.y = fmaxf(cr[1], 0.f);
            o0.z = fmaxf(cr[2], 0.f); o0.w = fmaxf(cr[3], 0.f);
            o1.x = fmaxf(cr[4], 0.f); o1.y = fmaxf(cr[5], 0.f);
            o1.z = fmaxf(cr[6], 0.f); o1.w = fmaxf(cr[7], 0.f);
            float4* op = reinterpret_cast<float4*>(out + (size_t)gnode * FEAT + f0);
            op[0] = o0;
            op[1] = o1;
        }
    }
}

// ---------------------------------------------------------------------------
extern "C" void kernel_launch(void* const* d_in, const int* in_sizes, int n_in,
                              void* d_out, int out_size, void* d_ws, size_t ws_size,
                              hipStream_t stream) {
    const float* h = (const float*)d_in[0];
    const float* w = (const float*)d_in[1];
    const float* gw = (const float*)d_in[2];
    const float* nrm = (const float*)d_in[3];
    const int* src = (const int*)d_in[4];
    const int* dst = (const int*)d_in[5];
    const int* rel = (const int*)d_in[6];
    float* out = (float*)d_out;

    const int N = in_sizes[0] / FEAT;
    const int E = in_sizes[4];
    const int nbk = (N + BN - 1) / BN;

    char* ws = (char*)d_ws;
    const size_t wt2B = align256((size_t)FEAT * KTOT * sizeof(bf16_t));   // 256 KiB
    const size_t hbB  = align256((size_t)N * FEAT * sizeof(bf16_t));      // 25.6 MB
    const size_t sgB  = align256((size_t)N * NRELS * sizeof(float));      // 3.2 MB
    const size_t cuB  = align256(((size_t)nbk * CPAD + 1) * sizeof(int)); // cursors+ovfcnt
    const size_t slB  = align256((size_t)nbk * ECAP * sizeof(PackedEdge)); // 6.4 MB
    const size_t ovB  = align256((size_t)E * sizeof(PackedEdge));

    bf16_t* wt2 = (bf16_t*)ws;
    bf16_t* hb = (bf16_t*)(ws + wt2B);
    float* sg = (float*)(ws + wt2B + hbB);
    int* cur = (int*)(ws + wt2B + hbB + sgB);          // [nbk*CPAD] + ovfcnt
    int* ovfcnt = cur + (size_t)nbk * CPAD;
    PackedEdge* slab = (PackedEdge*)(ws + wt2B + hbB + sgB + cuB);
    PackedEdge* ovfrec = (PackedEdge*)(ws + wt2B + hbB + sgB + cuB + slB);
    int* ovfbk = (int*)(ws + wt2B + hbB + sgB + cuB + slB + ovB);

    const int nprep = (N + 3) / 4;
    const int nwcv = (NRELS * FEAT * FEAT + 255) / 256;

    hipMemsetAsync(cur, 0, ((size_t)nbk * CPAD + 1) * sizeof(int), stream);
    k_phase1<<<nprep + nwcv, 256, 0, stream>>>(h, gw, w, sg, hb, wt2, nprep, N);
    k_fills<<<(E + 255) / 256, 256, 0, stream>>>(src, dst, rel, nrm, sg, cur, slab,
                                                 ovfrec, ovfbk, ovfcnt, E);
    k_aggemm<<<nbk, 512, 0, stream>>>(hb, wt2, slab, cur, ovfrec, ovfbk, ovfcnt,
                                      out, N);
}